// Round 2
// baseline (355.775 us; speedup 1.0000x reference)
//
#include <hip/hip_runtime.h>
#include <math.h>

#define BLOCK 256

typedef float f4v __attribute__((ext_vector_type(4)));

__device__ __forceinline__ void combine_md(float& m, float& d, float m2, float d2) {
    float nm = fmaxf(m, m2);
    d = d * __expf(m - nm) + d2 * __expf(m2 - nm);
    m = nm;
}

__device__ __forceinline__ void upd(float& m, float& d, float v) {
    // rare-taken max-update branch: one exp on the common path
    if (v > m) { d = d * __expf(m - v) + 1.f; m = v; }
    else       { d += __expf(v - m); }
}

// One block per row: online (max, sum-exp) + running sum, per-row loss to
// row_loss[row]; the last block to finish sums all rows into out[0]
// (deterministic: exactly one block, fixed summation order).
__global__ __launch_bounds__(BLOCK) void ls_fused(
    const float* __restrict__ logits, const int* __restrict__ target,
    float* __restrict__ row_loss, unsigned int* __restrict__ counter,
    float* __restrict__ out, int V, int rows,
    float conf, float smooth, float log_c, float log_s)
{
    const int row = blockIdx.x;
    const int tid = threadIdx.x;
    const f4v* rp = (const f4v*)(logits + (size_t)row * V);
    const int n4 = V >> 2;  // V=49408 -> n4 even, so (i, i+1) pairs never straddle the end

    float m0 = -3.0e38f, m1 = -3.0e38f, m2 = -3.0e38f, m3 = -3.0e38f;
    float d0 = 0.f, d1 = 0.f, d2 = 0.f, d3 = 0.f;
    float s  = 0.f;

    // unroll x2: two dwordx4 nontemporal loads issued before dependent math
    for (int i = 2 * tid; i < n4; i += 2 * BLOCK) {
        f4v a = __builtin_nontemporal_load(rp + i);
        f4v b = __builtin_nontemporal_load(rp + i + 1);
        s += ((a.x + a.y) + (a.z + a.w)) + ((b.x + b.y) + (b.z + b.w));
        upd(m0, d0, a.x); upd(m1, d1, a.y); upd(m2, d2, a.z); upd(m3, d3, a.w);
        upd(m0, d0, b.x); upd(m1, d1, b.y); upd(m2, d2, b.z); upd(m3, d3, b.w);
    }
    combine_md(m0, d0, m1, d1);
    combine_md(m2, d2, m3, d3);
    combine_md(m0, d0, m2, d2);

    // 64-lane butterfly (wave = 64)
    #pragma unroll
    for (int off = 32; off; off >>= 1) {
        float mm = __shfl_xor(m0, off);
        float dd = __shfl_xor(d0, off);
        s += __shfl_xor(s, off);
        combine_md(m0, d0, mm, dd);
    }

    __shared__ float sm[BLOCK / 64], sd[BLOCK / 64], ss[BLOCK / 64];
    __shared__ int is_last;
    const int lane = tid & 63, wv = tid >> 6;
    if (lane == 0) { sm[wv] = m0; sd[wv] = d0; ss[wv] = s; }
    __syncthreads();

    if (tid == 0) {
        float M = sm[0], D = sd[0], S = ss[0];
        #pragma unroll
        for (int w = 1; w < BLOCK / 64; ++w) {
            combine_md(M, D, sm[w], sd[w]);
            S += ss[w];
        }
        const int t = target[row];
        const float xt  = logits[(size_t)row * V + t];
        const float lse = M + logf(D);
        const float lq_t   = xt - lse;
        const float sum_lq = S - (float)V * lse;
        const float per = conf * (log_c - lq_t)
                        + smooth * ((float)(V - 1) * log_s - (sum_lq - lq_t));
        row_loss[row] = (t != 0) ? per : 0.f;  // IGNORE_INDEX = 0
        __threadfence();                        // release row_loss before arrival
        unsigned int prev = atomicAdd(counter, 1u);   // device-scope by default
        is_last = (prev == (unsigned int)(rows - 1));
    }
    __syncthreads();
    if (!is_last) return;

    // last block: deterministic fixed-order sum of all per-row losses
    __threadfence();  // acquire
    float fs = 0.f;
    for (int i = tid; i < rows; i += BLOCK) fs += row_loss[i];
    #pragma unroll
    for (int off = 32; off; off >>= 1) fs += __shfl_xor(fs, off);
    if (lane == 0) ss[wv] = fs;
    __syncthreads();
    if (tid == 0) out[0] = (ss[0] + ss[1]) + (ss[2] + ss[3]);
}

extern "C" void kernel_launch(void* const* d_in, const int* in_sizes, int n_in,
                              void* d_out, int out_size, void* d_ws, size_t ws_size,
                              hipStream_t stream)
{
    const float* logits = (const float*)d_in[0];
    const int*   target = (const int*)d_in[1];
    const int rows = in_sizes[1];
    const int V    = in_sizes[0] / rows;

    float* row_loss        = (float*)d_ws;                 // rows * 4 B
    unsigned int* counter  = (unsigned int*)((char*)d_ws + (size_t)rows * sizeof(float));

    // counter must be 0 at kernel start on EVERY call (d_ws is poisoned once
    // and never re-poisoned) -> on-stream memset, graph-capturable.
    hipMemsetAsync(counter, 0, sizeof(unsigned int), stream);

    const double conf   = 0.7;                    // 1 - LABEL_SMOOTHING
    const double smooth = 0.3 / (double)(V - 1);  // SMOOTH_VAL

    ls_fused<<<rows, BLOCK, 0, stream>>>(
        logits, target, row_loss, counter, (float*)d_out, V, rows,
        (float)conf, (float)smooth, (float)log(conf), (float)log(smooth));
}

// Round 3
// 345.186 us; speedup vs baseline: 1.0307x; 1.0307x over previous
//
#include <hip/hip_runtime.h>
#include <math.h>

#define BLOCK 256

typedef float f4v __attribute__((ext_vector_type(4)));

__device__ __forceinline__ void combine_md(float& m, float& d, float m2, float d2) {
    float nm = fmaxf(m, m2);
    d = d * __expf(m - nm) + d2 * __expf(m2 - nm);
    m = nm;
}

__device__ __forceinline__ void upd(float& m, float& d, float v) {
    // rare-taken max-update branch: one exp on the common path
    if (v > m) { d = d * __expf(m - v) + 1.f; m = v; }
    else       { d += __expf(v - m); }
}

// One block per row: online (max, sum-exp) + running sum, per-row loss to
// row_loss[row]; the last block to finish sums all rows into out[0]
// (deterministic: exactly one block performs a fixed-order sum).
__global__ __launch_bounds__(BLOCK) void ls_fused(
    const float* __restrict__ logits, const int* __restrict__ target,
    float* __restrict__ row_loss, unsigned int* __restrict__ counter,
    float* __restrict__ out, int V, int rows,
    float conf, float smooth, float log_c, float log_s)
{
    const int row = blockIdx.x;
    const int tid = threadIdx.x;
    const f4v* rp = (const f4v*)(logits + (size_t)row * V);
    const int n4 = V >> 2;                       // 12352 for V=49408
    const int nfull = (n4 / (4 * BLOCK)) * (4 * BLOCK);  // 12288

    float m0 = -3.0e38f, m1 = -3.0e38f, m2 = -3.0e38f, m3 = -3.0e38f;
    float d0 = 0.f, d1 = 0.f, d2 = 0.f, d3 = 0.f;
    float s  = 0.f;

    // unroll x4, block-contiguous: each load instruction's wave footprint is
    // 64 lanes x 16 B = 1024 B fully contiguous; 4 independent loads in flight.
    for (int i = tid; i < nfull; i += 4 * BLOCK) {
        f4v a = rp[i];
        f4v b = rp[i + BLOCK];
        f4v c = rp[i + 2 * BLOCK];
        f4v e = rp[i + 3 * BLOCK];
        s += ((a.x + a.y) + (a.z + a.w)) + ((b.x + b.y) + (b.z + b.w))
           + ((c.x + c.y) + (c.z + c.w)) + ((e.x + e.y) + (e.z + e.w));
        upd(m0, d0, a.x); upd(m1, d1, a.y); upd(m2, d2, a.z); upd(m3, d3, a.w);
        upd(m0, d0, b.x); upd(m1, d1, b.y); upd(m2, d2, b.z); upd(m3, d3, b.w);
        upd(m0, d0, c.x); upd(m1, d1, c.y); upd(m2, d2, c.z); upd(m3, d3, c.w);
        upd(m0, d0, e.x); upd(m1, d1, e.y); upd(m2, d2, e.z); upd(m3, d3, e.w);
    }
    for (int i = nfull + tid; i < n4; i += BLOCK) {   // tail (64 float4s)
        f4v a = rp[i];
        s += (a.x + a.y) + (a.z + a.w);
        upd(m0, d0, a.x); upd(m1, d1, a.y); upd(m2, d2, a.z); upd(m3, d3, a.w);
    }
    combine_md(m0, d0, m1, d1);
    combine_md(m2, d2, m3, d3);
    combine_md(m0, d0, m2, d2);

    // 64-lane butterfly (wave = 64)
    #pragma unroll
    for (int off = 32; off; off >>= 1) {
        float mm = __shfl_xor(m0, off);
        float dd = __shfl_xor(d0, off);
        s += __shfl_xor(s, off);
        combine_md(m0, d0, mm, dd);
    }

    __shared__ float sm[BLOCK / 64], sd[BLOCK / 64], ss[BLOCK / 64];
    __shared__ int is_last;
    const int lane = tid & 63, wv = tid >> 6;
    if (lane == 0) { sm[wv] = m0; sd[wv] = d0; ss[wv] = s; }
    __syncthreads();

    if (tid == 0) {
        float M = sm[0], D = sd[0], S = ss[0];
        #pragma unroll
        for (int w = 1; w < BLOCK / 64; ++w) {
            combine_md(M, D, sm[w], sd[w]);
            S += ss[w];
        }
        const int t = target[row];
        const float xt  = logits[(size_t)row * V + t];
        const float lse = M + logf(D);
        const float lq_t   = xt - lse;
        const float sum_lq = S - (float)V * lse;
        const float per = conf * (log_c - lq_t)
                        + smooth * ((float)(V - 1) * log_s - (sum_lq - lq_t));
        row_loss[row] = (t != 0) ? per : 0.f;  // IGNORE_INDEX = 0
        __threadfence();                        // release row_loss before arrival
        unsigned int prev = atomicAdd(counter, 1u);   // device-scope by default
        is_last = (prev == (unsigned int)(rows - 1));
    }
    __syncthreads();
    if (!is_last) return;

    // last block: deterministic fixed-order sum of all per-row losses
    __threadfence();  // acquire
    float fs = 0.f;
    for (int i = tid; i < rows; i += BLOCK) fs += row_loss[i];
    #pragma unroll
    for (int off = 32; off; off >>= 1) fs += __shfl_xor(fs, off);
    if (lane == 0) ss[wv] = fs;
    __syncthreads();
    if (tid == 0) out[0] = (ss[0] + ss[1]) + (ss[2] + ss[3]);
}

extern "C" void kernel_launch(void* const* d_in, const int* in_sizes, int n_in,
                              void* d_out, int out_size, void* d_ws, size_t ws_size,
                              hipStream_t stream)
{
    const float* logits = (const float*)d_in[0];
    const int*   target = (const int*)d_in[1];
    const int rows = in_sizes[1];
    const int V    = in_sizes[0] / rows;

    float* row_loss        = (float*)d_ws;                 // rows * 4 B
    unsigned int* counter  = (unsigned int*)((char*)d_ws + (size_t)rows * sizeof(float));

    // counter must be 0 at kernel start on EVERY call (d_ws is poisoned once,
    // never re-poisoned) -> on-stream memset, graph-capturable.
    hipMemsetAsync(counter, 0, sizeof(unsigned int), stream);

    const double conf   = 0.7;                    // 1 - LABEL_SMOOTHING
    const double smooth = 0.3 / (double)(V - 1);  // SMOOTH_VAL

    ls_fused<<<rows, BLOCK, 0, stream>>>(
        logits, target, row_loss, counter, (float*)d_out, V, rows,
        (float)conf, (float)smooth, (float)log(conf), (float)log(smooth));
}

// Round 4
// 152.021 us; speedup vs baseline: 2.3403x; 2.2706x over previous
//
#include <hip/hip_runtime.h>
#include <math.h>

#define BLOCK 256

typedef float f4v __attribute__((ext_vector_type(4)));

__device__ __forceinline__ void combine_md(float& m, float& d, float m2, float d2) {
    float nm = fmaxf(m, m2);
    d = d * __expf(m - nm) + d2 * __expf(m2 - nm);
    m = nm;
}

__device__ __forceinline__ void upd(float& m, float& d, float v) {
    // rare-taken max-update branch: one exp on the common path
    if (v > m) { d = d * __expf(m - v) + 1.f; m = v; }
    else       { d += __expf(v - m); }
}

// One block per row: online (max, sum-exp) + running sum over the row,
// then per-row smoothed-label KL term written to row_loss[row].
// NO cross-block fences/atomics: device-scope release fences force per-block
// L2 writebacks on the non-coherent-XCD-L2 MI355X and cost ~200us (R2/R3 A/B).
__global__ __launch_bounds__(BLOCK) void ls_row_kernel(
    const float* __restrict__ logits, const int* __restrict__ target,
    float* __restrict__ row_loss, int V,
    float conf, float smooth, float log_c, float log_s)
{
    const int row = blockIdx.x;
    const int tid = threadIdx.x;
    const f4v* rp = (const f4v*)(logits + (size_t)row * V);
    const int n4 = V >> 2;                               // 12352 for V=49408
    const int nfull = (n4 / (4 * BLOCK)) * (4 * BLOCK);  // 12288

    float m0 = -3.0e38f, m1 = -3.0e38f, m2 = -3.0e38f, m3 = -3.0e38f;
    float d0 = 0.f, d1 = 0.f, d2 = 0.f, d3 = 0.f;
    float s  = 0.f;

    // unroll x4, block-contiguous: each load instruction's wave footprint is
    // 64 lanes x 16 B = 1024 B fully contiguous; 4 independent loads in flight.
    for (int i = tid; i < nfull; i += 4 * BLOCK) {
        f4v a = rp[i];
        f4v b = rp[i + BLOCK];
        f4v c = rp[i + 2 * BLOCK];
        f4v e = rp[i + 3 * BLOCK];
        s += ((a.x + a.y) + (a.z + a.w)) + ((b.x + b.y) + (b.z + b.w))
           + ((c.x + c.y) + (c.z + c.w)) + ((e.x + e.y) + (e.z + e.w));
        upd(m0, d0, a.x); upd(m1, d1, a.y); upd(m2, d2, a.z); upd(m3, d3, a.w);
        upd(m0, d0, b.x); upd(m1, d1, b.y); upd(m2, d2, b.z); upd(m3, d3, b.w);
        upd(m0, d0, c.x); upd(m1, d1, c.y); upd(m2, d2, c.z); upd(m3, d3, c.w);
        upd(m0, d0, e.x); upd(m1, d1, e.y); upd(m2, d2, e.z); upd(m3, d3, e.w);
    }
    for (int i = nfull + tid; i < n4; i += BLOCK) {      // tail (64 float4s)
        f4v a = rp[i];
        s += (a.x + a.y) + (a.z + a.w);
        upd(m0, d0, a.x); upd(m1, d1, a.y); upd(m2, d2, a.z); upd(m3, d3, a.w);
    }
    combine_md(m0, d0, m1, d1);
    combine_md(m2, d2, m3, d3);
    combine_md(m0, d0, m2, d2);

    // 64-lane butterfly (wave = 64)
    #pragma unroll
    for (int off = 32; off; off >>= 1) {
        float mm = __shfl_xor(m0, off);
        float dd = __shfl_xor(d0, off);
        s += __shfl_xor(s, off);
        combine_md(m0, d0, mm, dd);
    }

    __shared__ float sm[BLOCK / 64], sd[BLOCK / 64], ss[BLOCK / 64];
    const int lane = tid & 63, wv = tid >> 6;
    if (lane == 0) { sm[wv] = m0; sd[wv] = d0; ss[wv] = s; }
    __syncthreads();

    if (tid == 0) {
        float M = sm[0], D = sd[0], S = ss[0];
        #pragma unroll
        for (int w = 1; w < BLOCK / 64; ++w) {
            combine_md(M, D, sm[w], sd[w]);
            S += ss[w];
        }
        const int t = target[row];
        const float xt  = logits[(size_t)row * V + t];
        const float lse = M + logf(D);
        const float lq_t   = xt - lse;
        const float sum_lq = S - (float)V * lse;
        const float per = conf * (log_c - lq_t)
                        + smooth * ((float)(V - 1) * log_s - (sum_lq - lq_t));
        row_loss[row] = (t != 0) ? per : 0.f;  // IGNORE_INDEX = 0
    }
}

// Deterministic single-block tree sum of the per-row losses (16 KB read).
__global__ __launch_bounds__(256) void ls_sum_kernel(
    const float* __restrict__ row_loss, float* __restrict__ out, int n)
{
    float s = 0.f;
    for (int i = threadIdx.x; i < n; i += 256) s += row_loss[i];
    #pragma unroll
    for (int off = 32; off; off >>= 1) s += __shfl_xor(s, off);
    __shared__ float ss[4];
    if ((threadIdx.x & 63) == 0) ss[threadIdx.x >> 6] = s;
    __syncthreads();
    if (threadIdx.x == 0) out[0] = (ss[0] + ss[1]) + (ss[2] + ss[3]);
}

extern "C" void kernel_launch(void* const* d_in, const int* in_sizes, int n_in,
                              void* d_out, int out_size, void* d_ws, size_t ws_size,
                              hipStream_t stream)
{
    const float* logits = (const float*)d_in[0];
    const int*   target = (const int*)d_in[1];
    const int rows = in_sizes[1];
    const int V    = in_sizes[0] / rows;

    float* row_loss = (float*)d_ws;  // rows * 4 bytes

    const double conf   = 0.7;                    // 1 - LABEL_SMOOTHING
    const double smooth = 0.3 / (double)(V - 1);  // SMOOTH_VAL

    ls_row_kernel<<<rows, BLOCK, 0, stream>>>(
        logits, target, row_loss, V,
        (float)conf, (float)smooth, (float)log(conf), (float)log(smooth));
    ls_sum_kernel<<<1, 256, 0, stream>>>(row_loss, (float*)d_out, rows);
}

// Round 5
// 129.694 us; speedup vs baseline: 2.7432x; 1.1722x over previous
//
#include <hip/hip_runtime.h>
#include <math.h>

#define BLOCK 256

typedef float f4v __attribute__((ext_vector_type(4)));

__device__ __forceinline__ void combine_md(float& m, float& d, float m2, float d2) {
    float nm = fmaxf(m, m2);
    d = d * __expf(m - nm) + d2 * __expf(m2 - nm);
    m = nm;
}

__device__ __forceinline__ void upd(float& m, float& d, float v) {
    // rare-taken max-update branch: one exp on the common path
    if (v > m) { d = d * __expf(m - v) + 1.f; m = v; }
    else       { d += __expf(v - m); }
}

// One block per row: online (max, sum-exp) + running sum over the row,
// then per-row smoothed-label KL term written to row_loss[row].
// NO cross-block fences/atomics: device-scope release fences force per-block
// L2 writebacks on the non-coherent-XCD-L2 MI355X and cost ~200us (R2/R3 A/B).
__global__ __launch_bounds__(BLOCK) void ls_row_kernel(
    const float* __restrict__ logits, const int* __restrict__ target,
    float* __restrict__ row_loss, int V,
    float conf, float smooth, float log_c, float log_s)
{
    const int row = blockIdx.x;
    const int tid = threadIdx.x;
    const f4v* rp = (const f4v*)(logits + (size_t)row * V);
    const int n4 = V >> 2;  // V divisible by 4 (49408)

    // Prefetch the target gather BEFORE the streaming loop so its ~900-cycle
    // HBM latency hides under the loop instead of serializing the epilogue.
    int   t  = 0;
    float xt = 0.f;
    if (tid == 0) {
        t  = target[row];
        xt = logits[(size_t)row * V + t];
    }

    // Simple stride-BLOCK loop (measured best, R1/R4 A/B): one 1024-B-
    // footprint dwordx4 per wave per step; nt -> no L2 allocate on streams.
    float m0 = -3.0e38f, m1 = -3.0e38f, m2 = -3.0e38f, m3 = -3.0e38f;
    float d0 = 0.f, d1 = 0.f, d2 = 0.f, d3 = 0.f;
    float s  = 0.f;

    for (int i = tid; i < n4; i += BLOCK) {
        f4v v = __builtin_nontemporal_load(rp + i);
        s += (v.x + v.y) + (v.z + v.w);
        upd(m0, d0, v.x); upd(m1, d1, v.y); upd(m2, d2, v.z); upd(m3, d3, v.w);
    }
    combine_md(m0, d0, m1, d1);
    combine_md(m2, d2, m3, d3);
    combine_md(m0, d0, m2, d2);

    // 64-lane butterfly (wave = 64)
    #pragma unroll
    for (int off = 32; off; off >>= 1) {
        float mm = __shfl_xor(m0, off);
        float dd = __shfl_xor(d0, off);
        s += __shfl_xor(s, off);
        combine_md(m0, d0, mm, dd);
    }

    __shared__ float sm[BLOCK / 64], sd[BLOCK / 64], ss[BLOCK / 64];
    const int lane = tid & 63, wv = tid >> 6;
    if (lane == 0) { sm[wv] = m0; sd[wv] = d0; ss[wv] = s; }
    __syncthreads();

    if (tid == 0) {
        float M = sm[0], D = sd[0], S = ss[0];
        #pragma unroll
        for (int w = 1; w < BLOCK / 64; ++w) {
            combine_md(M, D, sm[w], sd[w]);
            S += ss[w];
        }
        const float lse = M + logf(D);
        const float lq_t   = xt - lse;
        const float sum_lq = S - (float)V * lse;
        const float per = conf * (log_c - lq_t)
                        + smooth * ((float)(V - 1) * log_s - (sum_lq - lq_t));
        row_loss[row] = (t != 0) ? per : 0.f;  // IGNORE_INDEX = 0
    }
}

// Deterministic single-block tree sum of the per-row losses (16 KB read).
__global__ __launch_bounds__(256) void ls_sum_kernel(
    const float* __restrict__ row_loss, float* __restrict__ out, int n)
{
    float s = 0.f;
    for (int i = threadIdx.x; i < n; i += 256) s += row_loss[i];
    #pragma unroll
    for (int off = 32; off; off >>= 1) s += __shfl_xor(s, off);
    __shared__ float ss[4];
    if ((threadIdx.x & 63) == 0) ss[threadIdx.x >> 6] = s;
    __syncthreads();
    if (threadIdx.x == 0) out[0] = (ss[0] + ss[1]) + (ss[2] + ss[3]);
}

extern "C" void kernel_launch(void* const* d_in, const int* in_sizes, int n_in,
                              void* d_out, int out_size, void* d_ws, size_t ws_size,
                              hipStream_t stream)
{
    const float* logits = (const float*)d_in[0];
    const int*   target = (const int*)d_in[1];
    const int rows = in_sizes[1];
    const int V    = in_sizes[0] / rows;

    float* row_loss = (float*)d_ws;  // rows * 4 bytes

    const double conf   = 0.7;                    // 1 - LABEL_SMOOTHING
    const double smooth = 0.3 / (double)(V - 1);  // SMOOTH_VAL

    ls_row_kernel<<<rows, BLOCK, 0, stream>>>(
        logits, target, row_loss, V,
        (float)conf, (float)smooth, (float)log(conf), (float)log(smooth));
    ls_sum_kernel<<<1, 256, 0, stream>>>(row_loss, (float*)d_out, rows);
}